// Round 11
// baseline (132.531 us; speedup 1.0000x reference)
//
#include <hip/hip_runtime.h>
#include <hip/hip_bf16.h>
#include <stdint.h>

typedef __bf16 bf16_t;
typedef __bf16 bf16x8 __attribute__((ext_vector_type(8)));
typedef __bf16 bf16x4 __attribute__((ext_vector_type(4)));
typedef float  f32x4  __attribute__((ext_vector_type(4)));

#define DIM   1024
#define BATCH 8
#define NTOK  (BATCH * DIM)   /* 8192 */
#define SCALE 0.03125f        /* 1/sqrt(1024) */

// ---------------- f32 -> bf16 convert (vectorized) ----------------
__global__ void k_cvt(const float* __restrict__ in, bf16_t* __restrict__ out, int n4) {
    int i = blockIdx.x * blockDim.x + threadIdx.x;
    if (i < n4) {
        const float4 v = reinterpret_cast<const float4*>(in)[i];
        bf16x4 o;
        o.x = (bf16_t)v.x; o.y = (bf16_t)v.y; o.z = (bf16_t)v.z; o.w = (bf16_t)v.w;
        reinterpret_cast<bf16x4*>(out)[i] = o;
    }
}

// ============== K1: fused preamble (verbatim role bodies, index remap) ==============
__global__ __launch_bounds__(256)
void k_prep(const float* __restrict__ x, const float* __restrict__ Wqkv,
            const float* __restrict__ w,
            bf16_t* __restrict__ xb, bf16_t* __restrict__ wbig,
            bf16_t* __restrict__ wtb, bf16_t* __restrict__ wqt,
            float* __restrict__ bp32)
{
    __shared__ float tile[32][33];
    const int b = blockIdx.x;
    if (b < 8192) {
        const int i = b * 256 + threadIdx.x;
        const float4 v = reinterpret_cast<const float4*>(x)[i];
        bf16x4 o;
        o.x = (bf16_t)v.x; o.y = (bf16_t)v.y; o.z = (bf16_t)v.z; o.w = (bf16_t)v.w;
        reinterpret_cast<bf16x4*>(xb)[i] = o;
    } else if (b < 10240) {
        const int i = (b - 8192) * 256 + threadIdx.x;
        const float4 v = reinterpret_cast<const float4*>(Wqkv + 1048576)[i];
        bf16x4 o;
        o.x = (bf16_t)v.x; o.y = (bf16_t)v.y; o.z = (bf16_t)v.z; o.w = (bf16_t)v.w;
        reinterpret_cast<bf16x4*>(wbig + 1048576)[i] = o;
    } else if (b < 11264) {
        const int t  = b - 10240;
        const int tx = threadIdx.x & 31, ty = threadIdx.x >> 5;
        const int d0 = (t & 31) * 32, e0 = (t >> 5) * 32;
#pragma unroll
        for (int r = 0; r < 4; ++r) {
            const int d = d0 + r * 8 + ty;
            const int e = e0 + tx;
            tile[r * 8 + ty][tx] =
                w[d * 1024 + e] + w[1048576 + d * 1024 + e] + w[2097152 + d * 1024 + e];
        }
        __syncthreads();
#pragma unroll
        for (int r = 0; r < 4; ++r) {
            const int e = e0 + r * 8 + ty;
            const int d = d0 + tx;
            wtb[e * 1024 + d] = (bf16_t)tile[tx][r * 8 + ty];
        }
    } else if (b < 12288) {
        const int t  = b - 11264;
        const int tx = threadIdx.x & 31, ty = threadIdx.x >> 5;
        const int e0 = (t & 31) * 32, d0 = (t >> 5) * 32;
#pragma unroll
        for (int r = 0; r < 4; ++r)
            tile[r * 8 + ty][tx] = Wqkv[(long)(e0 + r * 8 + ty) * 1024 + d0 + tx];
        __syncthreads();
#pragma unroll
        for (int r = 0; r < 4; ++r)
            wqt[(long)(d0 + r * 8 + ty) * 1024 + e0 + tx] = (bf16_t)tile[tx][r * 8 + ty];
    } else {
        const int i = (b - 12288) * 256 + threadIdx.x;
        const f32x4 z = {0.f, 0.f, 0.f, 0.f};
        reinterpret_cast<f32x4*>(bp32)[i] = z;
    }
}

// ====== K2: bqw (wave-parallel dot) ∪ B' split-K GEMM (f32 atomicAdd) ======
__global__ __launch_bounds__(256)
void k_mid(const float* __restrict__ bq, const bf16_t* __restrict__ wtb,
           const bf16_t* __restrict__ wqt, float* __restrict__ bqwO,
           float* __restrict__ oAt)
{
    __shared__ __align__(16) bf16_t As[128 * 32];
    __shared__ __align__(16) bf16_t Bs[128 * 32];

    const int tid  = threadIdx.x;
    const int wave = tid >> 6;
    const int lane = tid & 63;

    if (blockIdx.x < 256) {
        const int n = blockIdx.x * 4 + wave;
        const bf16_t* row = wtb + (long)n * 1024;
        float s = 0.f;
#pragma unroll
        for (int c = 0; c < 2; ++c) {
            const int d0 = (lane + c * 64) * 8;
            const bf16x8 v = *reinterpret_cast<const bf16x8*>(row + d0);
#pragma unroll
            for (int e = 0; e < 8; ++e) s += bq[d0 + e] * (float)v[e];
        }
#pragma unroll
        for (int off = 32; off; off >>= 1) s += __shfl_down(s, off);
        if (lane == 0) bqwO[n] = s;
        return;
    }

    const int s  = blockIdx.x - 256;
    const int bm = (s >> 5) * 128;
    const int bn = ((s >> 2) & 7) * 128;
    const int kb = (s & 3) * 256;
    const int wr = wave >> 1, wc = wave & 1;
    const int lhi = lane >> 4, llo = lane & 15;

    f32x4 acc[4][4];
    const f32x4 fz = {0.f, 0.f, 0.f, 0.f};
#pragma unroll
    for (int i = 0; i < 4; ++i)
#pragma unroll
        for (int j = 0; j < 4; ++j) acc[i][j] = fz;

    for (int k0 = 0; k0 < 256; k0 += 32) {
#pragma unroll
        for (int i = 0; i < 2; ++i) {
            const int c  = wave * 128 + i * 64 + lane;
            const int r  = c >> 2;
            const int cc = (c & 3) << 3;
            const long ga = (long)(bm + r) * 1024 + kb + k0 + cc;
            const long gb = (long)(bn + r) * 1024 + kb + k0 + cc;
            const int lbase = (wave * 128 + i * 64) << 3;
            __builtin_amdgcn_global_load_lds(
                (const __attribute__((address_space(1))) uint32_t*)(wtb + ga),
                (__attribute__((address_space(3))) uint32_t*)(&As[lbase]), 16, 0, 0);
            __builtin_amdgcn_global_load_lds(
                (const __attribute__((address_space(1))) uint32_t*)(wqt + gb),
                (__attribute__((address_space(3))) uint32_t*)(&Bs[lbase]), 16, 0, 0);
        }
        __syncthreads();

        bf16x8 af[4], bfr[4];
#pragma unroll
        for (int mi = 0; mi < 4; ++mi)
            af[mi] = *reinterpret_cast<const bf16x8*>(&As[(wr * 64 + mi * 16 + llo) * 32 + lhi * 8]);
#pragma unroll
        for (int ni = 0; ni < 4; ++ni)
            bfr[ni] = *reinterpret_cast<const bf16x8*>(&Bs[(wc * 64 + ni * 16 + llo) * 32 + lhi * 8]);
#pragma unroll
        for (int mi = 0; mi < 4; ++mi)
#pragma unroll
            for (int ni = 0; ni < 4; ++ni)
                acc[mi][ni] = __builtin_amdgcn_mfma_f32_16x16x32_bf16(af[mi], bfr[ni], acc[mi][ni], 0, 0, 0);
        __syncthreads();
    }

#pragma unroll
    for (int mi = 0; mi < 4; ++mi) {
        const int r0 = bm + wr * 64 + mi * 16 + lhi * 4;
#pragma unroll
        for (int ni = 0; ni < 4; ++ni) {
            const int cg = bn + wc * 64 + ni * 16 + llo;
            const f32x4 v = acc[mi][ni];
#pragma unroll
            for (int j = 0; j < 4; ++j)
                atomicAdd(&oAt[(long)(r0 + j) * 1024 + cg], v[j]);
        }
    }
}

// ====== BM=128 x BN_, BK=32, dbuf, 40KB LDS -> 4 blocks/CU (full occupancy) ======
// C[m][n] = sum_k A[m][k]*B[n][k], K=1024 (NTT=32 tiles of BK=32).
// 8 waves (2M x 4N): per-wave 64 x BN_/4. LDS: 2 x (8KB A + BN_*64B B).
// Sync/tile: { stage2(t+1) [A+B0, 2 loads all thr]; vmcnt(2) [forces ALL of
//   tile t landed incl. t's stage3, never waits on t+1]; barrier;
//   stage3(t+1) [waves0-3, B rows 128..191, BN_=192 only]; 7 ds_reads;
//   setprio 12 MFMA; lgkmcnt(0); barrier }.
// Swizzle (R5-proven, 0 conflicts): 64B rows paired into 128B lines;
//   phys chunk = (((r&1)<<2)|c) ^ (line&7); staged via inverse-swizzled src.
__device__ __forceinline__ int swz(int r, int c) {
    return ((r >> 1) << 7) | (((((r & 1) << 2) | c) ^ ((r >> 1) & 7)) << 4);
}
#define GLOAD(SRC, DST) __builtin_amdgcn_global_load_lds( \
    (const __attribute__((address_space(1))) uint32_t*)(SRC), \
    (__attribute__((address_space(3))) uint32_t*)(DST), 16, 0, 0)

template<int BN_, int MODE>
__global__ __launch_bounds__(512, 4)
void k_db(const bf16_t* __restrict__ A, const bf16_t* __restrict__ Bp,
          const float* __restrict__ bqw, const float* __restrict__ bqkv,
          bf16_t* __restrict__ oQW, bf16_t* __restrict__ oK, float* __restrict__ oF)
{
    constexpr int NF   = BN_ / 64;          // n-frags per wave: 3 or 2
    constexpr int SLOT = 8192 + BN_ * 64;   // bytes per buffer (20480 / 16384)
    constexpr int NTT  = 32;                // K / 32
    __shared__ __align__(16) unsigned char slds[2 * SLOT];

    const int tid  = threadIdx.x;
    const int wave = tid >> 6, lane = tid & 63;
    const int wm = wave >> 2, wn = wave & 3;
    const int llo = lane & 15, lhi = lane >> 4;

    int bm, bn; long zz = 0;
    if (MODE == 1) {
        bm = blockIdx.x * 128; bn = blockIdx.y * BN_;
    } else {
        const int nw = ((int)blockIdx.x & 7) * 64 + ((int)blockIdx.x >> 3);
        zz = (long)(nw >> 6) << 20;         // batch = XCD id (L2-resident qw/k)
        const int r = nw & 63;
        bm = (r >> 3) * 128; bn = (r & 7) * 128;
    }

    // ---- per-thread inverse-swizzled staging sources + linear LDS dests ----
    // chunk C -> line L=C>>3, slot s=C&7; u = s ^ (L&7); row r=(L<<1)|(u>>2);
    // elem offset ce=(u&3)<<3. dst = C<<4 (linear).
    const bf16_t *spA, *spB0, *spB1 = nullptr;
    int dA, dB0, dB1 = 0;
    {
        const int C = tid, L = C >> 3, u = (C & 7) ^ (L & 7);
        const int r = (L << 1) | (u >> 2), ce = (u & 3) << 3;
        spA = A + zz + (long)(bm + r) * 1024 + ce;  dA = C << 4;
        spB0 = Bp + zz + (long)(bn + r) * 1024 + ce; dB0 = 8192 + (C << 4);
    }
    if (BN_ == 192 && wave < 4) {
        const int C = 512 + tid, L = C >> 3, u = (C & 7) ^ (L & 7);
        const int r = (L << 1) | (u >> 2), ce = (u & 3) << 3;
        spB1 = Bp + zz + (long)(bn + r) * 1024 + ce; dB1 = 8192 + (C << 4);
    }

    f32x4 acc[4][NF];
    const f32x4 fz = {0.f, 0.f, 0.f, 0.f};
#pragma unroll
    for (int i = 0; i < 4; ++i)
#pragma unroll
        for (int j = 0; j < NF; ++j) acc[i][j] = fz;

    // prologue: tile 0 fully staged
    {
        unsigned char* s0 = slds;
        GLOAD(spA, s0 + dA); GLOAD(spB0, s0 + dB0);
        if (BN_ == 192 && wave < 4) GLOAD(spB1, s0 + dB1);
    }

    for (int t = 0; t < NTT; ++t) {
        if (t + 1 < NTT) {
            unsigned char* sn = slds + ((t + 1) & 1) * SLOT;
            const long ko = (long)(t + 1) << 5;
            GLOAD(spA + ko, sn + dA); GLOAD(spB0 + ko, sn + dB0);
            asm volatile("s_waitcnt vmcnt(2)" ::: "memory");
        } else {
            asm volatile("s_waitcnt vmcnt(0)" ::: "memory");
        }
        __builtin_amdgcn_s_barrier();
        if (t + 1 < NTT && BN_ == 192 && wave < 4) {
            unsigned char* sn = slds + ((t + 1) & 1) * SLOT;
            GLOAD(spB1 + ((long)(t + 1) << 5), sn + dB1);
        }

        const unsigned char* sb = slds + (t & 1) * SLOT;
        bf16x8 af[4], bfv[NF];
#pragma unroll
        for (int mi = 0; mi < 4; ++mi) {
            const int r = wm * 64 + mi * 16 + llo;
            af[mi] = *reinterpret_cast<const bf16x8*>(sb + swz(r, lhi));
        }
#pragma unroll
        for (int ni = 0; ni < NF; ++ni) {
            const int r = wn * (NF * 16) + ni * 16 + llo;
            bfv[ni] = *reinterpret_cast<const bf16x8*>(sb + 8192 + swz(r, lhi));
        }
        __builtin_amdgcn_s_setprio(1);
#pragma unroll
        for (int mi = 0; mi < 4; ++mi)
#pragma unroll
            for (int ni = 0; ni < NF; ++ni)
                acc[mi][ni] = __builtin_amdgcn_mfma_f32_16x16x32_bf16(
                    af[mi], bfv[ni], acc[mi][ni], 0, 0, 0);
        __builtin_amdgcn_s_setprio(0);
        // all LDS reads of this buffer retired before it can be restaged
        asm volatile("s_waitcnt lgkmcnt(0)" ::: "memory");
        __builtin_amdgcn_s_barrier();
    }

    // ---------------- epilogue ----------------
#pragma unroll
    for (int mi = 0; mi < 4; ++mi) {
        const long r0 = bm + wm * 64 + mi * 16 + lhi * 4;
#pragma unroll
        for (int ni = 0; ni < NF; ++ni) {
            const int cg = bn + wn * (NF * 16) + ni * 16 + llo;
            const f32x4 v = acc[mi][ni];
            if (MODE == 1) {
                const int sec = cg >> 10;
                const int c1  = cg & 1023;
                const float bb = (sec == 0) ? bqw[cg] : bqkv[cg];
#pragma unroll
                for (int j = 0; j < 4; ++j) {
                    const long idx = (r0 + j) * 1024 + c1;
                    const float val = v[j] + bb;
                    if (sec == 0)      oQW[idx] = (bf16_t)val;
                    else if (sec == 1) oK[idx] = (bf16_t)val;
                    else               oF[idx] = val;
                }
            } else {
#pragma unroll
                for (int j = 0; j < 4; ++j) {
                    const long idx = zz + (r0 + j) * 1024 + cg;
                    oF[idx] = oF[idx] + SCALE * v[j];
                }
            }
        }
    }
}
#undef GLOAD

extern "C" void kernel_launch(void* const* d_in, const int* in_sizes, int n_in,
                              void* d_out, int out_size, void* d_ws, size_t ws_size,
                              hipStream_t stream) {
    const float* x    = (const float*)d_in[0];
    const float* Wqkv = (const float*)d_in[1];
    const float* bqkv = (const float*)d_in[2];
    const float* w    = (const float*)d_in[3];
    float* out = (float*)d_out;

    // workspace layout (54 MiB + 64 KiB)
    char* ws = (char*)d_ws;
    bf16_t* xb   = (bf16_t*)(ws);                          // 16 MiB
    bf16_t* wbig = (bf16_t*)(ws + (16l << 20));            // 6 MiB: [B'; Wk; Wv]
    float*  bqw  = (float*) (ws + (22l << 20));            // 4 KiB (64 KiB reserved)
    bf16_t* kb   = (bf16_t*)(ws + (22l << 20) + 65536);    // 16 MiB
    bf16_t* qwb  = (bf16_t*)(ws + (38l << 20) + 65536);    // 16 MiB (region reused)
    bf16_t* wtb  = qwb;                    // 2 MiB WeffT   (dead before qwb written)
    bf16_t* wqt  = qwb + 1048576;          // 2 MiB WqT     (dead before qwb written)
    float*  bp32 = (float*)(qwb + 2097152);// 4 MiB f32 B'  (dead before qwb written)
    if (ws_size < (size_t)(54l << 20) + 65536) return;

    // K1: fused preamble (x-cvt | Wkv-cvt | WeffT | WqT | bp32-zero)
    k_prep<<<13312, 256, 0, stream>>>(x, Wqkv, w, xb, wbig, wtb, wqt, bp32);

    // K2: bqw dot + B' split-K GEMM (atomicAdd into bp32)
    k_mid<<<512, 256, 0, stream>>>(bqkv, wtb, wqt, bqw, bp32);

    // K3: B' f32 -> bf16 into wbig rows [0,1024)
    k_cvt<<<1024, 256, 0, stream>>>(bp32, wbig, 262144);

    // fused projection: [qw | k | v] = x @ wbig^T + bias; 1024 blocks = 1 round @ 4/CU
    k_db<192, 1><<<dim3(64, 16), 512, 0, stream>>>(xb, wbig, bqw, bqkv, qwb, kb, out);

    // scores: out += SCALE * qw @ k^T; 512 blocks, XCD = batch
    k_db<128, 2><<<dim3(512), 512, 0, stream>>>(qwb, kb, nullptr, nullptr,
                                                nullptr, nullptr, out);
}

// Round 12
// 109.112 us; speedup vs baseline: 1.2146x; 1.2146x over previous
//
#include <hip/hip_runtime.h>
#include <hip/hip_bf16.h>
#include <stdint.h>

typedef __bf16 bf16_t;
typedef __bf16 bf16x8 __attribute__((ext_vector_type(8)));
typedef __bf16 bf16x4 __attribute__((ext_vector_type(4)));
typedef float  f32x4  __attribute__((ext_vector_type(4)));

#define DIM   1024
#define BATCH 8
#define NTOK  (BATCH * DIM)   /* 8192 */
#define SCALE 0.03125f        /* 1/sqrt(1024) */

// ============== K1: fused preamble (verbatim role bodies, index remap) ==============
// blocks [0,8192):      xb = bf16(x)                  (2097152 f32x4)
// blocks [8192,10240):  wbig[1M..] = bf16(Wqkv[1M..]) (524288 f32x4)
// blocks [10240,11264): wtb = WeffT (transpose-sum of w), 32x32 tiles
// blocks [11264,12288): wqt = WqT (transpose of Wqkv rows [0,1024)), 32x32 tiles
__global__ __launch_bounds__(256)
void k_prep(const float* __restrict__ x, const float* __restrict__ Wqkv,
            const float* __restrict__ w,
            bf16_t* __restrict__ xb, bf16_t* __restrict__ wbig,
            bf16_t* __restrict__ wtb, bf16_t* __restrict__ wqt)
{
    __shared__ float tile[32][33];
    const int b = blockIdx.x;
    if (b < 8192) {
        const int i = b * 256 + threadIdx.x;
        const float4 v = reinterpret_cast<const float4*>(x)[i];
        bf16x4 o;
        o.x = (bf16_t)v.x; o.y = (bf16_t)v.y; o.z = (bf16_t)v.z; o.w = (bf16_t)v.w;
        reinterpret_cast<bf16x4*>(xb)[i] = o;
    } else if (b < 10240) {
        const int i = (b - 8192) * 256 + threadIdx.x;
        const float4 v = reinterpret_cast<const float4*>(Wqkv + 1048576)[i];
        bf16x4 o;
        o.x = (bf16_t)v.x; o.y = (bf16_t)v.y; o.z = (bf16_t)v.z; o.w = (bf16_t)v.w;
        reinterpret_cast<bf16x4*>(wbig + 1048576)[i] = o;
    } else if (b < 11264) {
        const int t  = b - 10240;
        const int tx = threadIdx.x & 31, ty = threadIdx.x >> 5;
        const int d0 = (t & 31) * 32, e0 = (t >> 5) * 32;
#pragma unroll
        for (int r = 0; r < 4; ++r) {
            const int d = d0 + r * 8 + ty;
            const int e = e0 + tx;
            tile[r * 8 + ty][tx] =
                w[d * 1024 + e] + w[1048576 + d * 1024 + e] + w[2097152 + d * 1024 + e];
        }
        __syncthreads();
#pragma unroll
        for (int r = 0; r < 4; ++r) {
            const int e = e0 + r * 8 + ty;
            const int d = d0 + tx;
            wtb[e * 1024 + d] = (bf16_t)tile[tx][r * 8 + ty];
        }
    } else {
        const int t  = b - 11264;
        const int tx = threadIdx.x & 31, ty = threadIdx.x >> 5;
        const int e0 = (t & 31) * 32, d0 = (t >> 5) * 32;
#pragma unroll
        for (int r = 0; r < 4; ++r)
            tile[r * 8 + ty][tx] = Wqkv[(long)(e0 + r * 8 + ty) * 1024 + d0 + tx];
        __syncthreads();
#pragma unroll
        for (int r = 0; r < 4; ++r)
            wqt[(long)(d0 + r * 8 + ty) * 1024 + e0 + tx] = (bf16_t)tile[tx][r * 8 + ty];
    }
}

// ====== K2: bqw (wave-parallel dot) ∪ B' split-K GEMM (4 partial buffers) ======
// blocks [0,256):   bqw[n] = sum_d bq[d] * wtb[n*1024+d], n = blk*4+wave
// blocks [256,512): split-K GEMM; s = blk-256: bm=(s>>5)*128, bn=((s>>2)&7)*128,
//                   ks=s&3 (K window [ks*256, ks*256+256)); partial -> oP[ks].
__global__ __launch_bounds__(256)
void k_mid(const float* __restrict__ bq, const bf16_t* __restrict__ wtb,
           const bf16_t* __restrict__ wqt, float* __restrict__ bqwO,
           float* __restrict__ oP)
{
    __shared__ __align__(16) bf16_t As[128 * 32];
    __shared__ __align__(16) bf16_t Bs[128 * 32];

    const int tid  = threadIdx.x;
    const int wave = tid >> 6;
    const int lane = tid & 63;

    if (blockIdx.x < 256) {
        const int n = blockIdx.x * 4 + wave;
        const bf16_t* row = wtb + (long)n * 1024;
        float s = 0.f;
#pragma unroll
        for (int c = 0; c < 2; ++c) {
            const int d0 = (lane + c * 64) * 8;
            const bf16x8 v = *reinterpret_cast<const bf16x8*>(row + d0);
#pragma unroll
            for (int e = 0; e < 8; ++e) s += bq[d0 + e] * (float)v[e];
        }
#pragma unroll
        for (int off = 32; off; off >>= 1) s += __shfl_down(s, off);
        if (lane == 0) bqwO[n] = s;
        return;
    }

    const int s  = blockIdx.x - 256;
    const int bm = (s >> 5) * 128;
    const int bn = ((s >> 2) & 7) * 128;
    const int kb = (s & 3) * 256;
    float* outP  = oP + (long)(s & 3) * 1048576;
    const int wr = wave >> 1, wc = wave & 1;
    const int lhi = lane >> 4, llo = lane & 15;

    f32x4 acc[4][4];
    const f32x4 fz = {0.f, 0.f, 0.f, 0.f};
#pragma unroll
    for (int i = 0; i < 4; ++i)
#pragma unroll
        for (int j = 0; j < 4; ++j) acc[i][j] = fz;

    for (int k0 = 0; k0 < 256; k0 += 32) {
#pragma unroll
        for (int i = 0; i < 2; ++i) {
            const int c  = wave * 128 + i * 64 + lane;
            const int r  = c >> 2;
            const int cc = (c & 3) << 3;
            const long ga = (long)(bm + r) * 1024 + kb + k0 + cc;
            const long gb = (long)(bn + r) * 1024 + kb + k0 + cc;
            const int lbase = (wave * 128 + i * 64) << 3;
            __builtin_amdgcn_global_load_lds(
                (const __attribute__((address_space(1))) uint32_t*)(wtb + ga),
                (__attribute__((address_space(3))) uint32_t*)(&As[lbase]), 16, 0, 0);
            __builtin_amdgcn_global_load_lds(
                (const __attribute__((address_space(1))) uint32_t*)(wqt + gb),
                (__attribute__((address_space(3))) uint32_t*)(&Bs[lbase]), 16, 0, 0);
        }
        __syncthreads();

        bf16x8 af[4], bfr[4];
#pragma unroll
        for (int mi = 0; mi < 4; ++mi)
            af[mi] = *reinterpret_cast<const bf16x8*>(&As[(wr * 64 + mi * 16 + llo) * 32 + lhi * 8]);
#pragma unroll
        for (int ni = 0; ni < 4; ++ni)
            bfr[ni] = *reinterpret_cast<const bf16x8*>(&Bs[(wc * 64 + ni * 16 + llo) * 32 + lhi * 8]);
#pragma unroll
        for (int mi = 0; mi < 4; ++mi)
#pragma unroll
            for (int ni = 0; ni < 4; ++ni)
                acc[mi][ni] = __builtin_amdgcn_mfma_f32_16x16x32_bf16(af[mi], bfr[ni], acc[mi][ni], 0, 0, 0);
        __syncthreads();
    }

#pragma unroll
    for (int mi = 0; mi < 4; ++mi) {
        const int r0 = bm + wr * 64 + mi * 16 + lhi * 4;
#pragma unroll
        for (int ni = 0; ni < 4; ++ni) {
            const int cg = bn + wc * 64 + ni * 16 + llo;
            const f32x4 v = acc[mi][ni];
#pragma unroll
            for (int j = 0; j < 4; ++j)
                outP[(long)(r0 + j) * 1024 + cg] = v[j];
        }
    }
}

// ---------------- K3: B' = bf16( sum of 4 partials ) ----------------
__global__ __launch_bounds__(256)
void k_cvt4(const float* __restrict__ p, bf16_t* __restrict__ out) {
    const int i = blockIdx.x * 256 + threadIdx.x;   // 262144 f32x4 groups
    const f32x4* rp = reinterpret_cast<const f32x4*>(p);
    const f32x4 a = rp[i];
    const f32x4 b = rp[i + 262144];
    const f32x4 c = rp[i + 524288];
    const f32x4 d = rp[i + 786432];
    bf16x4 o;
    o.x = (bf16_t)(a.x + b.x + c.x + d.x);
    o.y = (bf16_t)(a.y + b.y + c.y + d.y);
    o.z = (bf16_t)(a.z + b.z + c.z + d.z);
    o.w = (bf16_t)(a.w + b.w + c.w + d.w);
    reinterpret_cast<bf16x4*>(out)[i] = o;
}

// ========== BM=128 x BN_, BK=64, double-buffered, swizzled LDS (R10-proven) ==========
// C[m][n] = sum_k A[m][k] * B[n][k], K=1024 (16 tiles of BK=64).
// 8 waves (2M x 4N): per-wave 64 x BN_/4. LDS: 2 x (128+BN_)*128B (80/64 KB)
// -> 2 blocks/CU. Sync per tile: { stage(t+1); vmcnt(LPT) [t landed, t+1 in
// flight]; barrier; reads+MFMA (2 k-halves); lgkmcnt(0); barrier }.
// Swizzle: rows are 128B (8 x 16B chunks); phys chunk = logical ^ (row & 7)
// (involution; staged linearly from inverse-swizzled global source).
// MODE 1 (BN_=192): qkv projection epilogue (q/k/v routing + bias), grid 64x16.
// MODE 2 (BN_=128): oF[z + m*1024+n] += SCALE*acc, flat grid 512, XCD = batch.
template<int BN_, int MODE>
__global__ __launch_bounds__(512, 2)
void k_db(const bf16_t* __restrict__ A, const bf16_t* __restrict__ Bp,
          const float* __restrict__ bqw, const float* __restrict__ bqkv,
          bf16_t* __restrict__ oQW, bf16_t* __restrict__ oK, float* __restrict__ oF)
{
    constexpr int NF   = BN_ / 64;          // n-frags per wave: 3 or 2
    constexpr int LB   = BN_ / 64;          // B loads/thread: 3 or 2
    constexpr int LPT  = 2 + LB;            // loads/thread/tile
    constexpr int SLOT = (128 + BN_) * 128; // bytes per buffer
    constexpr int NTT  = 16;                // K / 64
    __shared__ __align__(16) unsigned char slds[2 * SLOT];

    const int tid  = threadIdx.x;
    const int wave = tid >> 6, lane = tid & 63;
    const int wm = wave >> 2, wn = wave & 3;
    const int llo = lane & 15, lhi = lane >> 4;

    int bm, bn; long zz = 0;
    if (MODE == 1) {
        bm = blockIdx.x * 128; bn = blockIdx.y * BN_;
    } else {
        const int nw = ((int)blockIdx.x & 7) * 64 + ((int)blockIdx.x >> 3);
        zz = (long)(nw >> 6) << 20;         // batch = XCD id (L2-resident qw/k)
        const int r = nw & 63;
        bm = (r >> 3) * 128; bn = (r & 7) * 128;
    }

    // per-thread inverse-swizzled staging sources + linear LDS dests
    const bf16_t* sp[LPT]; int dst[LPT];
#pragma unroll
    for (int j = 0; j < 2; ++j) {
        const int C = j * 512 + tid;        // A chunk id, 0..1023
        const int r = C >> 3, u = (C & 7) ^ (r & 7);
        sp[j] = A + zz + (long)(bm + r) * 1024 + (u << 3);
        dst[j] = C << 4;
    }
#pragma unroll
    for (int j = 0; j < LB; ++j) {
        const int C = j * 512 + tid;        // B chunk id, 0..BN_*8-1
        const int r = C >> 3, u = (C & 7) ^ (r & 7);
        sp[2 + j] = Bp + zz + (long)(bn + r) * 1024 + (u << 3);
        dst[2 + j] = 16384 + (C << 4);
    }

    auto stage = [&](int tt) {
        unsigned char* s = &slds[(tt & 1) * SLOT];
        const long ko = (long)tt << 6;
#pragma unroll
        for (int j = 0; j < LPT; ++j)
            __builtin_amdgcn_global_load_lds(
                (const __attribute__((address_space(1))) uint32_t*)(sp[j] + ko),
                (__attribute__((address_space(3))) uint32_t*)(s + dst[j]), 16, 0, 0);
    };

    f32x4 acc[4][NF];
    const f32x4 fz = {0.f, 0.f, 0.f, 0.f};
#pragma unroll
    for (int i = 0; i < 4; ++i)
#pragma unroll
        for (int j = 0; j < NF; ++j) acc[i][j] = fz;

    stage(0);

    for (int t = 0; t < NTT; ++t) {
        if (t + 1 < NTT) {
            stage(t + 1);
            asm volatile("s_waitcnt vmcnt(%0)" :: "i"(LPT) : "memory");
        } else {
            asm volatile("s_waitcnt vmcnt(0)" ::: "memory");
        }
        __builtin_amdgcn_s_barrier();

        const unsigned char* sb = &slds[(t & 1) * SLOT];
#pragma unroll
        for (int ks = 0; ks < 2; ++ks) {
            bf16x8 af[4], bfv[NF];
#pragma unroll
            for (int mi = 0; mi < 4; ++mi) {
                const int r = wm * 64 + mi * 16 + llo;
                af[mi] = *reinterpret_cast<const bf16x8*>(
                    sb + r * 128 + ((((ks << 2) | lhi) ^ (r & 7)) << 4));
            }
#pragma unroll
            for (int ni = 0; ni < NF; ++ni) {
                const int r = wn * (NF * 16) + ni * 16 + llo;
                bfv[ni] = *reinterpret_cast<const bf16x8*>(
                    sb + 16384 + r * 128 + ((((ks << 2) | lhi) ^ (r & 7)) << 4));
            }
            __builtin_amdgcn_s_setprio(1);
#pragma unroll
            for (int mi = 0; mi < 4; ++mi)
#pragma unroll
                for (int ni = 0; ni < NF; ++ni)
                    acc[mi][ni] = __builtin_amdgcn_mfma_f32_16x16x32_bf16(
                        af[mi], bfv[ni], acc[mi][ni], 0, 0, 0);
            __builtin_amdgcn_s_setprio(0);
        }
        // all LDS reads of this buffer retired before it can be restaged
        asm volatile("s_waitcnt lgkmcnt(0)" ::: "memory");
        __builtin_amdgcn_s_barrier();
    }

    // ---------------- epilogue ----------------
#pragma unroll
    for (int mi = 0; mi < 4; ++mi) {
        const long r0 = bm + wm * 64 + mi * 16 + lhi * 4;
#pragma unroll
        for (int ni = 0; ni < NF; ++ni) {
            const int cg = bn + wn * (NF * 16) + ni * 16 + llo;
            const f32x4 v = acc[mi][ni];
            if (MODE == 1) {
                const int sec = cg >> 10;
                const int c1  = cg & 1023;
                const float bb = (sec == 0) ? bqw[cg] : bqkv[cg];
#pragma unroll
                for (int j = 0; j < 4; ++j) {
                    const long idx = (r0 + j) * 1024 + c1;
                    const float val = v[j] + bb;
                    if (sec == 0)      oQW[idx] = (bf16_t)val;
                    else if (sec == 1) oK[idx] = (bf16_t)val;
                    else               oF[idx] = val;
                }
            } else {
#pragma unroll
                for (int j = 0; j < 4; ++j) {
                    const long idx = zz + (r0 + j) * 1024 + cg;
                    oF[idx] = oF[idx] + SCALE * v[j];
                }
            }
        }
    }
}

extern "C" void kernel_launch(void* const* d_in, const int* in_sizes, int n_in,
                              void* d_out, int out_size, void* d_ws, size_t ws_size,
                              hipStream_t stream) {
    const float* x    = (const float*)d_in[0];
    const float* Wqkv = (const float*)d_in[1];
    const float* bqkv = (const float*)d_in[2];
    const float* w    = (const float*)d_in[3];
    float* out = (float*)d_out;

    // workspace layout (54 MiB + 64 KiB)
    char* ws = (char*)d_ws;
    bf16_t* xb   = (bf16_t*)(ws);                          // 16 MiB
    bf16_t* wbig = (bf16_t*)(ws + (16l << 20));            // 6 MiB: [B'; Wk; Wv]
    float*  bqw  = (float*) (ws + (22l << 20));            // 4 KiB (64 KiB reserved)
    bf16_t* kb   = (bf16_t*)(ws + (22l << 20) + 65536);    // 16 MiB (k output)
    float*  part = (float*) kb;            // 16 MiB B' partials (dead before kb written)
    bf16_t* qwb  = (bf16_t*)(ws + (38l << 20) + 65536);    // 16 MiB (qw output; region reused)
    bf16_t* wtb  = qwb;                    // 2 MiB WeffT   (dead before qwb written)
    bf16_t* wqt  = qwb + 1048576;          // 2 MiB WqT     (dead before qwb written)
    if (ws_size < (size_t)(54l << 20) + 65536) return;

    // K1: fused preamble (x-cvt | Wkv-cvt | WeffT | WqT)
    k_prep<<<12288, 256, 0, stream>>>(x, Wqkv, w, xb, wbig, wtb, wqt);

    // K2: bqw dot + B' split-K GEMM (4 partial f32 buffers, no atomics)
    k_mid<<<512, 256, 0, stream>>>(bqkv, wtb, wqt, bqw, part);

    // K3: B' = bf16(sum of partials) -> wbig rows [0,1024)
    k_cvt4<<<1024, 256, 0, stream>>>(part, wbig);

    // fused projection: [qw | k | v] = x @ wbig^T + bias; 1024 blocks = 2 exact rounds
    k_db<192, 1><<<dim3(64, 16), 512, 0, stream>>>(xb, wbig, bqw, bqkv, qwb, kb, out);

    // scores: out += SCALE * qw @ k^T; 512 blocks, XCD = batch
    k_db<128, 2><<<dim3(512), 512, 0, stream>>>(qwb, kb, nullptr, nullptr,
                                                nullptr, nullptr, out);
}